// Round 15
// baseline (214.950 us; speedup 1.0000x reference)
//
#include <hip/hip_runtime.h>
#include <hip/hip_bf16.h>

#define Bc 512
#define Lc 512
#define Tc 128
#define GB 16     // batches per block
#define NW 4      // waves per block; wave w owns j-tiles {2w, 2w+1} = js [32w, 32w+32)

typedef __attribute__((ext_vector_type(8))) short bf16x8;
typedef __attribute__((ext_vector_type(4))) float f32x4;
typedef __attribute__((ext_vector_type(2))) unsigned u32x2;

// raw barrier: drain LDS ops only; global prefetches stay in flight
__device__ __forceinline__ void bar_lgkm() {
  asm volatile("s_waitcnt lgkmcnt(0)\n\ts_barrier" ::: "memory");
}
__device__ __forceinline__ unsigned short f2bf_u(float f) {
  __hip_bfloat16 h = __float2bfloat16(f);
  unsigned short us;
  __builtin_memcpy(&us, &h, 2);
  return us;
}
__device__ __forceinline__ short f2bf(float f) { return (short)f2bf_u(f); }
__device__ __forceinline__ unsigned pk2(float a, float b) {
  return (unsigned)f2bf_u(a) | ((unsigned)f2bf_u(b) << 16);
}

__global__ __launch_bounds__(256, 1) __attribute__((amdgpu_waves_per_eu(1, 1)))
void crf_forward(const float* __restrict__ x,      // [B,L,T]
                 const float* __restrict__ trans,  // [T,T]
                 const float* __restrict__ startT, // [T]
                 const float* __restrict__ endT,   // [T]
                 const int*   __restrict__ labels, // [B,L]
                 const int*   __restrict__ mask,   // [B,L]
                 float* __restrict__ diff_out,     // [B]
                 float* __restrict__ msum_out)     // [B]
{
  // Abar bf16, swizzled: elem(b, j) = b*128 + (j ^ ((b&7)<<3)); double-buffered
  __shared__ __align__(16) unsigned short Pl[2][GB * Tc];
  __shared__ __align__(16) float r_s[GB];   // per-batch rescale bcast
  __shared__ unsigned char anyz[Lc];        // any mask==0 at t
  __shared__ __align__(16) float c_s[GB];
  __shared__ float score_s[GB];
  __shared__ float msum_s[GB];
  __shared__ float red[GB][NW];

  const int tid  = threadIdx.x;     // 0..255 (4 waves)
  const int lane = tid & 63;
  const int w    = tid >> 6;        // wave 0..3
  const int crow = lane & 15;       // A-operand: row-in-tile; B/C: batch
  const int khi  = lane >> 4;       // 0..3
  const int bg0  = blockIdx.x * GB;
  const bool rl  = (w == 0) && (khi == 0);  // 16 lanes own r/c for batch=crow

  // ---- stage anyz flags (one-time) ----
  for (int t = tid; t < Lc; t += 256) {
    unsigned zz = 0;
    for (int bb = 0; bb < GB; ++bb)
      zz |= (unsigned)(mask[(size_t)(bg0 + bb) * Lc + t] == 0);
    anyz[t] = (unsigned char)zz;
  }

  // ---- gold-path score + msum: wave w handles local batches 4w..4w+3 ----
  for (int bb = 4 * w; bb < 4 * w + 4; ++bb) {
    const int bglob = bg0 + bb;
    const int* lbp = labels + (size_t)bglob * Lc;
    const int* mkp = mask + (size_t)bglob * Lc;
    const float* xrow = x + (size_t)bglob * Lc * Tc;
    float sp = 0.f, msp = 0.f;
    for (int t = lane; t < Lc; t += 64) {
      int l0 = lbp[t];
      int m0 = mkp[t];
      msp += (float)m0;
      if (t < Lc - 1) {
        int l1 = lbp[t + 1];
        float m1 = (float)mkp[t + 1];
        sp += trans[l0 * Tc + l1] * m1 + xrow[(size_t)t * Tc + l0] * (float)m0;
      }
    }
#pragma unroll
    for (int off = 32; off; off >>= 1) {
      sp += __shfl_xor(sp, off);
      msp += __shfl_xor(msp, off);
    }
    if (lane == 0) {
      int last_idx = (int)msp - 1;
      int lt = lbp[last_idx];
      score_s[bb] = sp + startT[lbp[0]] + endT[lt]
                  + xrow[(size_t)(Lc - 1) * Tc + lt] * (float)mkp[Lc - 1];
      msum_s[bb] = msp;
    }
  }

  // ---- E^T fragments (A-operand), 2 j-tiles: lane holds, for tile q and
  //      k-chunk Q, A[row=crow][k=32Q+8khi+e] = exp(trans[k*128 + (32w+16q+crow)])
  //      8 frags = 32 VGPRs ----
  bf16x8 E00, E01, E02, E03, E10, E11, E12, E13;
  {
    const int jr0 = 32 * w + crow;
    const int jr1 = jr0 + 16;
#pragma unroll
    for (int e = 0; e < 8; ++e) {
      E00[e] = f2bf(__expf(trans[(     8 * khi + e) * Tc + jr0]));
      E01[e] = f2bf(__expf(trans[(32 + 8 * khi + e) * Tc + jr0]));
      E02[e] = f2bf(__expf(trans[(64 + 8 * khi + e) * Tc + jr0]));
      E03[e] = f2bf(__expf(trans[(96 + 8 * khi + e) * Tc + jr0]));
      E10[e] = f2bf(__expf(trans[(     8 * khi + e) * Tc + jr1]));
      E11[e] = f2bf(__expf(trans[(32 + 8 * khi + e) * Tc + jr1]));
      E12[e] = f2bf(__expf(trans[(64 + 8 * khi + e) * Tc + jr1]));
      E13[e] = f2bf(__expf(trans[(96 + 8 * khi + e) * Tc + jr1]));
    }
  }

  // ---- per-lane constant offsets ----
  const int sw   = (crow & 7) << 3;           // XOR swizzle key (elem units)
  const int boff = crow * Tc;
  const int ro0  = boff + (( 0 + 8 * khi) ^ sw);  // B-frag b128 reads (full K)
  const int ro1  = boff + ((32 + 8 * khi) ^ sw);
  const int ro2  = boff + ((64 + 8 * khi) ^ sw);
  const int ro3  = boff + ((96 + 8 * khi) ^ sw);
  const int wo0  = boff + ((32 * w      + 4 * khi) ^ sw);  // b64 packed stores
  const int wo1  = boff + ((32 * w + 16 + 4 * khi) ^ sw);
  // x: lane reads x[b=crow][t] at j = 32w+4khi(+16) as f32x4 pairs
  const float* xp = x + (size_t)(bg0 + crow) * Lc * Tc + 32 * w + 4 * khi;
  const int*   mkl = mask + (size_t)(bg0 + crow) * Lc;

  __syncthreads();  // anyz staged

  // ---- init: alpha_0 = start + x_0; exact renorm by alpha_0[b][0] ----
  f32x4 st0 = *(const f32x4*)&startT[32 * w + 4 * khi];
  f32x4 st1 = *(const f32x4*)&startT[32 * w + 16 + 4 * khi];
  f32x4 a00 = st0 + *(const f32x4*)xp;
  f32x4 a01 = st1 + *(const f32x4*)(xp + 16);
  if (rl) r_s[crow] = a00.x;        // rl lanes have j0 = 0
  __syncthreads();
  float cb = r_s[crow];
  f32x4 Ao0, Ao1;
  Ao0.x = __expf(a00.x - cb); Ao0.y = __expf(a00.y - cb);
  Ao0.z = __expf(a00.z - cb); Ao0.w = __expf(a00.w - cb);
  Ao1.x = __expf(a01.x - cb); Ao1.y = __expf(a01.y - cb);
  Ao1.z = __expf(a01.z - cb); Ao1.w = __expf(a01.w - cb);
  {
    u32x2 p0 = {pk2(Ao0.x, Ao0.y), pk2(Ao0.z, Ao0.w)};
    u32x2 p1 = {pk2(Ao1.x, Ao1.y), pk2(Ao1.z, Ao1.w)};
    *(u32x2*)&Pl[1][wo0] = p0;
    *(u32x2*)&Pl[1][wo1] = p1;
  }
  float c  = rl ? cb : 0.f;
  float lr = 0.f;                   // pending c-increment for next APPLY
  __syncthreads();                  // cb consumed -> safe to overwrite r_s
  if (rl) r_s[crow] = 1.f;          // first APPLY multiplies by 1
  // ---- depth-2 x prefetch (2 tiles each) ----
  f32x4 xA0 = *(const f32x4*)(xp + 1 * Tc);
  f32x4 xA1 = *(const f32x4*)(xp + 1 * Tc + 16);
  f32x4 xB0 = *(const f32x4*)(xp + 2 * Tc);
  f32x4 xB1 = *(const f32x4*)(xp + 2 * Tc + 16);
  __syncthreads();                  // Pl[1], r_s visible

  // Phases: 1=APPLY (read r_s, scale, c+=lr), 2=PLAIN, 0=COMPUTE (rl lanes:
  // exponent of new Abar[b][0] -> r_s, lr). az: rare general-mask path.
#define MFMA_(A, B, C_) C_ = __builtin_amdgcn_mfma_f32_16x16x32_bf16(A, B, C_, 0, 0, 0)
#define STEP(T, RB, WB, PH, XQ0, XQ1) do {                                     \
    bf16x8 Bf0 = *(const bf16x8*)&Pl[RB][ro0];                                 \
    bf16x8 Bf1 = *(const bf16x8*)&Pl[RB][ro1];                                 \
    bf16x8 Bf2 = *(const bf16x8*)&Pl[RB][ro2];                                 \
    bf16x8 Bf3 = *(const bf16x8*)&Pl[RB][ro3];                                 \
    unsigned char az = anyz[T];                                                \
    f32x4 ex0, ex1;                                                            \
    ex0.x = __expf(XQ0.x); ex0.y = __expf(XQ0.y);                              \
    ex0.z = __expf(XQ0.z); ex0.w = __expf(XQ0.w);                              \
    ex1.x = __expf(XQ1.x); ex1.y = __expf(XQ1.y);                              \
    ex1.z = __expf(XQ1.z); ex1.w = __expf(XQ1.w);                              \
    { int tp__ = (T) + 2; if (tp__ > Lc - 1) tp__ = Lc - 1;                    \
      XQ0 = *(const f32x4*)(xp + (size_t)tp__ * Tc);                           \
      XQ1 = *(const f32x4*)(xp + (size_t)tp__ * Tc + 16); }                    \
    f32x4 Ca0 = {0.f,0.f,0.f,0.f}, Cb0 = {0.f,0.f,0.f,0.f};                    \
    f32x4 Ca1 = {0.f,0.f,0.f,0.f}, Cb1 = {0.f,0.f,0.f,0.f};                    \
    MFMA_(E00, Bf0, Ca0); MFMA_(E10, Bf0, Ca1);                                \
    MFMA_(E02, Bf2, Cb0); MFMA_(E12, Bf2, Cb1);                                \
    MFMA_(E01, Bf1, Ca0); MFMA_(E11, Bf1, Ca1);                                \
    MFMA_(E03, Bf3, Cb0); MFMA_(E13, Bf3, Cb1);                                \
    f32x4 Cr0 = Ca0 + Cb0, Cr1 = Ca1 + Cb1;                                    \
    f32x4 v0, v1;                                                              \
    if ((PH) == 1) {                                                           \
      float rr = r_s[crow];                                                    \
      v0.x = Cr0.x * rr * ex0.x; v0.y = Cr0.y * rr * ex0.y;                    \
      v0.z = Cr0.z * rr * ex0.z; v0.w = Cr0.w * rr * ex0.w;                    \
      v1.x = Cr1.x * rr * ex1.x; v1.y = Cr1.y * rr * ex1.y;                    \
      v1.z = Cr1.z * rr * ex1.z; v1.w = Cr1.w * rr * ex1.w;                    \
    } else {                                                                   \
      v0.x = Cr0.x * ex0.x; v0.y = Cr0.y * ex0.y;                              \
      v0.z = Cr0.z * ex0.z; v0.w = Cr0.w * ex0.w;                              \
      v1.x = Cr1.x * ex1.x; v1.y = Cr1.y * ex1.y;                              \
      v1.z = Cr1.z * ex1.z; v1.w = Cr1.w * ex1.w;                              \
    }                                                                          \
    if (az) {  /* rare general-mask path (per-lane batch) */                   \
      int m = mkl[T];                                                          \
      Ao0.x = m ? v0.x : Ao0.x; Ao0.y = m ? v0.y : Ao0.y;                      \
      Ao0.z = m ? v0.z : Ao0.z; Ao0.w = m ? v0.w : Ao0.w;                      \
      Ao1.x = m ? v1.x : Ao1.x; Ao1.y = m ? v1.y : Ao1.y;                      \
      Ao1.z = m ? v1.z : Ao1.z; Ao1.w = m ? v1.w : Ao1.w;                      \
      if ((PH) == 1 && rl) c += m ? lr : 0.f;                                  \
    } else {                                                                   \
      Ao0 = v0; Ao1 = v1;                                                      \
      if ((PH) == 1 && rl) c += lr;                                            \
    }                                                                          \
    {                                                                          \
      u32x2 p0 = {pk2(Ao0.x, Ao0.y), pk2(Ao0.z, Ao0.w)};                       \
      u32x2 p1 = {pk2(Ao1.x, Ao1.y), pk2(Ao1.z, Ao1.w)};                       \
      *(u32x2*)&Pl[WB][wo0] = p0;                                              \
      *(u32x2*)&Pl[WB][wo1] = p1;                                              \
    }                                                                          \
    if ((PH) == 0 && rl) {  /* COMPUTE: exponent of new Abar[b][0] */          \
      int E_ = (int)((__float_as_uint(Ao0.x) >> 23) & 0xffu) - 127;            \
      lr = (float)E_ * 0.6931471805599453f;                                    \
      r_s[crow] = __uint_as_float((unsigned)(127 - E_) << 23);                 \
    }                                                                          \
    bar_lgkm();                                                                \
  } while (0)

  // main: groups of 4 (phases 1,2,2,0); tail 509 (APPLY), 510, 511 (PLAIN)
  for (int t = 1; t <= Lc - 4; t += 4) {
    STEP(t,     1, 0, 1, xA0, xA1);
    STEP(t + 1, 0, 1, 2, xB0, xB1);
    STEP(t + 2, 1, 0, 2, xA0, xA1);
    STEP(t + 3, 0, 1, 0, xB0, xB1);
  }
  STEP(Lc - 3, 1, 0, 1, xA0, xA1);
  STEP(Lc - 2, 0, 1, 2, xB0, xB1);
  STEP(Lc - 1, 1, 0, 2, xA0, xA1);
#undef STEP
#undef MFMA_

  // ---- logZ_b = c_b + log(sum_j Abar[b][j] * exp(end[j])) ----
  if (rl) c_s[crow] = c;
  f32x4 ev0 = *(const f32x4*)&endT[32 * w + 4 * khi];
  f32x4 ev1 = *(const f32x4*)&endT[32 * w + 16 + 4 * khi];
  float part = Ao0.x * __expf(ev0.x) + Ao0.y * __expf(ev0.y)
             + Ao0.z * __expf(ev0.z) + Ao0.w * __expf(ev0.w)
             + Ao1.x * __expf(ev1.x) + Ao1.y * __expf(ev1.y)
             + Ao1.z * __expf(ev1.z) + Ao1.w * __expf(ev1.w);
  part += __shfl_xor(part, 16);
  part += __shfl_xor(part, 32);
  if (khi == 0) red[crow][w] = part;
  __syncthreads();
  if (tid < GB) {
    float tot = 0.f;
#pragma unroll
    for (int ww = 0; ww < NW; ++ww) tot += red[tid][ww];
    float logZ = c_s[tid] + __logf(tot);
    diff_out[bg0 + tid] = logZ - score_s[tid];
    msum_out[bg0 + tid] = msum_s[tid];
  }
}

__global__ __launch_bounds__(512)
void crf_final(const float* __restrict__ diff, const float* __restrict__ msum,
               float* __restrict__ out)
{
  __shared__ float sd[512];
  __shared__ float sm[512];
  int t = threadIdx.x;
  sd[t] = diff[t];
  sm[t] = msum[t];
  __syncthreads();
  for (int s = 256; s > 0; s >>= 1) {
    if (t < s) { sd[t] += sd[t + s]; sm[t] += sm[t + s]; }
    __syncthreads();
  }
  if (t == 0) out[0] = sd[0] / sm[0];
}

extern "C" void kernel_launch(void* const* d_in, const int* in_sizes, int n_in,
                              void* d_out, int out_size, void* d_ws, size_t ws_size,
                              hipStream_t stream) {
  const float* x      = (const float*)d_in[0];
  const float* trans  = (const float*)d_in[1];
  const float* startT = (const float*)d_in[2];
  const float* endT   = (const float*)d_in[3];
  const int*   labels = (const int*)d_in[4];
  const int*   mask   = (const int*)d_in[5];
  float* out = (float*)d_out;
  float* ws  = (float*)d_ws;
  float* diff = ws;        // [512]
  float* msum = ws + Bc;   // [512]

  crf_forward<<<dim3(Bc / GB), dim3(256), 0, stream>>>(
      x, trans, startT, endT, labels, mask, diff, msum);
  crf_final<<<dim3(1), dim3(512), 0, stream>>>(diff, msum, out);
}

// Round 16
// 168.655 us; speedup vs baseline: 1.2745x; 1.2745x over previous
//
#include <hip/hip_runtime.h>
#include <hip/hip_bf16.h>

#define Bc 512
#define Lc 512
#define Tc 128
#define GB 16     // batches per block
#define NW 8      // waves per block

typedef __attribute__((ext_vector_type(8))) short bf16x8;
typedef __attribute__((ext_vector_type(4))) float f32x4;
typedef __attribute__((ext_vector_type(2))) unsigned u32x2;

// raw barrier: drain LDS ops only; global prefetches stay in flight
__device__ __forceinline__ void bar_lgkm() {
  asm volatile("s_waitcnt lgkmcnt(0)\n\ts_barrier" ::: "memory");
}
__device__ __forceinline__ unsigned short f2bf_u(float f) {
  __hip_bfloat16 h = __float2bfloat16(f);
  unsigned short us;
  __builtin_memcpy(&us, &h, 2);
  return us;
}
__device__ __forceinline__ short f2bf(float f) { return (short)f2bf_u(f); }
__device__ __forceinline__ unsigned pk2(float a, float b) {
  return (unsigned)f2bf_u(a) | ((unsigned)f2bf_u(b) << 16);
}

__global__ __launch_bounds__(512, 1)
void crf_forward(const float* __restrict__ x,      // [B,L,T]
                 const float* __restrict__ trans,  // [T,T]
                 const float* __restrict__ startT, // [T]
                 const float* __restrict__ endT,   // [T]
                 const int*   __restrict__ labels, // [B,L]
                 const int*   __restrict__ mask,   // [B,L]
                 float* __restrict__ diff_out,     // [B]
                 float* __restrict__ msum_out)     // [B]
{
  // Abar bf16, swizzled: elem(b, j) = b*128 + (j ^ ((b&7)<<3)); double-buffered
  __shared__ __align__(16) unsigned short Pl[2][GB * Tc];
  __shared__ __align__(16) float r_s[GB];   // per-batch rescale bcast
  __shared__ unsigned azw[Lc / 32];         // bit t: any mask==0 at step t
  __shared__ __align__(16) float c_s[GB];
  __shared__ float score_s[GB];
  __shared__ float msum_s[GB];
  __shared__ float red[GB][NW];

  const int tid  = threadIdx.x;
  const int lane = tid & 63;
  const int w    = tid >> 6;        // wave 0..7 owns j-tile [16w,16w+16)
  const int crow = lane & 15;       // A-operand: j-row-in-tile; B/C: batch
  const int khi  = lane >> 4;       // 0..3
  const int bg0  = blockIdx.x * GB;
  const bool rl  = (w == 0) && (khi == 0);  // 16 lanes own r/c for batch=crow

  // ---- build any-zero bitmask words (one-time) ----
  if (tid < Lc / 32) azw[tid] = 0u;
  __syncthreads();
  if (tid < Lc) {
    unsigned zz = 0;
    for (int bb = 0; bb < GB; ++bb)
      zz |= (unsigned)(mask[(size_t)(bg0 + bb) * Lc + tid] == 0);
    if (zz) atomicOr(&azw[tid >> 5], 1u << (tid & 31));
  }

  // ---- gold-path score + msum: wave w handles local batches 2w, 2w+1 ----
  for (int bb = 2 * w; bb < 2 * w + 2; ++bb) {
    const int bglob = bg0 + bb;
    const int* lbp = labels + (size_t)bglob * Lc;
    const int* mkp = mask + (size_t)bglob * Lc;
    const float* xrow = x + (size_t)bglob * Lc * Tc;
    float sp = 0.f, msp = 0.f;
    for (int t = lane; t < Lc; t += 64) {
      int l0 = lbp[t];
      int m0 = mkp[t];
      msp += (float)m0;
      if (t < Lc - 1) {
        int l1 = lbp[t + 1];
        float m1 = (float)mkp[t + 1];
        sp += trans[l0 * Tc + l1] * m1 + xrow[(size_t)t * Tc + l0] * (float)m0;
      }
    }
#pragma unroll
    for (int off = 32; off; off >>= 1) {
      sp += __shfl_xor(sp, off);
      msp += __shfl_xor(msp, off);
    }
    if (lane == 0) {
      int last_idx = (int)msp - 1;
      int lt = lbp[last_idx];
      score_s[bb] = sp + startT[lbp[0]] + endT[lt]
                  + xrow[(size_t)(Lc - 1) * Tc + lt] * (float)mkp[Lc - 1];
      msum_s[bb] = msp;
    }
  }

  // ---- E^T fragments (A-operand): lane holds A[row=crow][k=32Q+8khi+e]
  //      = exp(trans[k*128 + (16w+crow)]); 16 VGPRs ----
  bf16x8 Ef0, Ef1, Ef2, Ef3;
  {
    const int jr = 16 * w + crow;
#pragma unroll
    for (int e = 0; e < 8; ++e) Ef0[e] = f2bf(__expf(trans[(     8 * khi + e) * Tc + jr]));
#pragma unroll
    for (int e = 0; e < 8; ++e) Ef1[e] = f2bf(__expf(trans[(32 + 8 * khi + e) * Tc + jr]));
#pragma unroll
    for (int e = 0; e < 8; ++e) Ef2[e] = f2bf(__expf(trans[(64 + 8 * khi + e) * Tc + jr]));
#pragma unroll
    for (int e = 0; e < 8; ++e) Ef3[e] = f2bf(__expf(trans[(96 + 8 * khi + e) * Tc + jr]));
  }

  // ---- per-lane constant offsets ----
  const int sw   = (crow & 7) << 3;           // XOR swizzle key (elem units)
  const int boff = crow * Tc;
  const int ro0  = boff + (( 0 + 8 * khi) ^ sw);  // B-frag b128 reads
  const int ro1  = boff + ((32 + 8 * khi) ^ sw);
  const int ro2  = boff + ((64 + 8 * khi) ^ sw);
  const int ro3  = boff + ((96 + 8 * khi) ^ sw);
  const int wo   = boff + ((16 * w + 4 * khi) ^ sw);  // b64 packed store
  // x: lane reads x[b=crow][t][16w+4khi .. +3] as one f32x4
  const float* xp = x + (size_t)(bg0 + crow) * Lc * Tc + 16 * w + 4 * khi;
  const int*   mkl = mask + (size_t)(bg0 + crow) * Lc;  // per-lane mask row

  __syncthreads();  // azw staged

  // ---- init: alpha_0 = start + x_0; exact renorm by alpha_0[b][0] ----
  f32x4 st4 = *(const f32x4*)&startT[16 * w + 4 * khi];
  f32x4 a0  = st4 + *(const f32x4*)xp;
  if (rl) r_s[crow] = a0.x;         // rl lanes have j0 = 0
  __syncthreads();
  float cb = r_s[crow];
  f32x4 Ao;
  Ao.x = __expf(a0.x - cb); Ao.y = __expf(a0.y - cb);
  Ao.z = __expf(a0.z - cb); Ao.w = __expf(a0.w - cb);
  {
    u32x2 pv = {pk2(Ao.x, Ao.y), pk2(Ao.z, Ao.w)};
    *(u32x2*)&Pl[1][wo] = pv;
  }
  float c  = rl ? cb : 0.f;
  float lr = 0.f;                   // pending c-increment for next APPLY
  __syncthreads();                  // cb consumed -> safe to overwrite r_s
  if (rl) r_s[crow] = 1.f;          // first APPLY multiplies by 1
  // ---- depth-2 x prefetch ----
  f32x4 xA = *(const f32x4*)(xp + 1 * Tc);
  f32x4 xB = *(const f32x4*)(xp + 2 * Tc);
  __syncthreads();                  // Pl[1], r_s visible

  // Phases by t mod 4: 0=COMPUTE (rl: exponent of new Abar[b][0] -> r_s, lr),
  // 1=APPLY (read r_s, scale, c+=lr), 2/3=PLAIN. AZ: scalar bit test (SGPR word).
#define MFMA_(A, B, C_) C_ = __builtin_amdgcn_mfma_f32_16x16x32_bf16(A, B, C_, 0, 0, 0)
#define STEP(T, RB, WB, PH, XQ, AZ) do {                                       \
    bf16x8 Bf0 = *(const bf16x8*)&Pl[RB][ro0];                                 \
    bf16x8 Bf1 = *(const bf16x8*)&Pl[RB][ro1];                                 \
    bf16x8 Bf2 = *(const bf16x8*)&Pl[RB][ro2];                                 \
    bf16x8 Bf3 = *(const bf16x8*)&Pl[RB][ro3];                                 \
    f32x4 ex;                                                                  \
    ex.x = __expf(XQ.x); ex.y = __expf(XQ.y);                                  \
    ex.z = __expf(XQ.z); ex.w = __expf(XQ.w);                                  \
    { int tp__ = (T) + 2; if (tp__ > Lc - 1) tp__ = Lc - 1;                    \
      XQ = *(const f32x4*)(xp + (size_t)tp__ * Tc); }                          \
    f32x4 Ca = {0.f, 0.f, 0.f, 0.f};                                           \
    f32x4 Cb2 = {0.f, 0.f, 0.f, 0.f};                                          \
    MFMA_(Ef0, Bf0, Ca);  MFMA_(Ef2, Bf2, Cb2);                                \
    MFMA_(Ef1, Bf1, Ca);  MFMA_(Ef3, Bf3, Cb2);                                \
    f32x4 Cr = Ca + Cb2;                                                       \
    f32x4 v;                                                                   \
    if ((PH) == 1) {                                                           \
      float rr = r_s[crow];                                                    \
      v.x = Cr.x * rr * ex.x; v.y = Cr.y * rr * ex.y;                          \
      v.z = Cr.z * rr * ex.z; v.w = Cr.w * rr * ex.w;                          \
    } else {                                                                   \
      v.x = Cr.x * ex.x; v.y = Cr.y * ex.y;                                    \
      v.z = Cr.z * ex.z; v.w = Cr.w * ex.w;                                    \
    }                                                                          \
    if (AZ) {  /* rare general-mask path (uniform branch) */                   \
      int m = mkl[T];                                                          \
      Ao.x = m ? v.x : Ao.x; Ao.y = m ? v.y : Ao.y;                            \
      Ao.z = m ? v.z : Ao.z; Ao.w = m ? v.w : Ao.w;                            \
      if ((PH) == 1 && rl) c += m ? lr : 0.f;                                  \
    } else {                                                                   \
      Ao = v;                                                                  \
      if ((PH) == 1 && rl) c += lr;                                            \
    }                                                                          \
    {                                                                          \
      u32x2 pv = {pk2(Ao.x, Ao.y), pk2(Ao.z, Ao.w)};                           \
      *(u32x2*)&Pl[WB][wo] = pv;                                               \
    }                                                                          \
    if ((PH) == 0 && rl) {  /* COMPUTE: exponent of new Abar[b][0] */          \
      int E0 = (int)((__float_as_uint(Ao.x) >> 23) & 0xffu) - 127;             \
      lr = (float)E0 * 0.6931471805599453f;                                    \
      r_s[crow] = __uint_as_float((unsigned)(127 - E0) << 23);                 \
    }                                                                          \
    bar_lgkm();                                                                \
  } while (0)

#define AZBIT(T) ((int)((curw >> ((T) & 31)) & 1u))

  // ---- main: 32-step groups, mask word held in SGPR via readfirstlane ----
  // t mod 4 phases: 0=COMPUTE, 1=APPLY, 2,3=PLAIN. Buffers: t odd RB=1, even RB=0.
  {
    unsigned curw = __builtin_amdgcn_readfirstlane(azw[0]);
    STEP(1, 1, 0, 1, xA, AZBIT(1));
    STEP(2, 0, 1, 2, xB, AZBIT(2));
    STEP(3, 1, 0, 2, xA, AZBIT(3));
    for (int t = 4; t < 32; t += 4) {
      STEP(t,     0, 1, 0, xB, AZBIT(t));
      STEP(t + 1, 1, 0, 1, xA, AZBIT(t + 1));
      STEP(t + 2, 0, 1, 2, xB, AZBIT(t + 2));
      STEP(t + 3, 1, 0, 2, xA, AZBIT(t + 3));
    }
  }
  for (int w5 = 1; w5 < Lc / 32; ++w5) {
    unsigned curw = __builtin_amdgcn_readfirstlane(azw[w5]);
    const int tb = w5 << 5;
    for (int t = tb; t < tb + 32; t += 4) {
      STEP(t,     0, 1, 0, xB, AZBIT(t));
      STEP(t + 1, 1, 0, 1, xA, AZBIT(t + 1));
      STEP(t + 2, 0, 1, 2, xB, AZBIT(t + 2));
      STEP(t + 3, 1, 0, 2, xA, AZBIT(t + 3));
    }
  }
#undef AZBIT
#undef STEP
#undef MFMA_

  // ---- logZ_b = c_b + log(sum_j Abar[b][j] * exp(end[j])) ----
  if (rl) c_s[crow] = c;
  f32x4 ev = *(const f32x4*)&endT[16 * w + 4 * khi];
  float part = Ao.x * __expf(ev.x) + Ao.y * __expf(ev.y)
             + Ao.z * __expf(ev.z) + Ao.w * __expf(ev.w);
  part += __shfl_xor(part, 16);
  part += __shfl_xor(part, 32);
  if (khi == 0) red[crow][w] = part;
  __syncthreads();
  if (tid < GB) {
    float tot = 0.f;
#pragma unroll
    for (int ww = 0; ww < NW; ++ww) tot += red[tid][ww];
    float logZ = c_s[tid] + __logf(tot);
    diff_out[bg0 + tid] = logZ - score_s[tid];
    msum_out[bg0 + tid] = msum_s[tid];
  }
}

__global__ __launch_bounds__(512)
void crf_final(const float* __restrict__ diff, const float* __restrict__ msum,
               float* __restrict__ out)
{
  __shared__ float sd[512];
  __shared__ float sm[512];
  int t = threadIdx.x;
  sd[t] = diff[t];
  sm[t] = msum[t];
  __syncthreads();
  for (int s = 256; s > 0; s >>= 1) {
    if (t < s) { sd[t] += sd[t + s]; sm[t] += sm[t + s]; }
    __syncthreads();
  }
  if (t == 0) out[0] = sd[0] / sm[0];
}

extern "C" void kernel_launch(void* const* d_in, const int* in_sizes, int n_in,
                              void* d_out, int out_size, void* d_ws, size_t ws_size,
                              hipStream_t stream) {
  const float* x      = (const float*)d_in[0];
  const float* trans  = (const float*)d_in[1];
  const float* startT = (const float*)d_in[2];
  const float* endT   = (const float*)d_in[3];
  const int*   labels = (const int*)d_in[4];
  const int*   mask   = (const int*)d_in[5];
  float* out = (float*)d_out;
  float* ws  = (float*)d_ws;
  float* diff = ws;        // [512]
  float* msum = ws + Bc;   // [512]

  crf_forward<<<dim3(Bc / GB), dim3(512), 0, stream>>>(
      x, trans, startT, endT, labels, mask, diff, msum);
  crf_final<<<dim3(1), dim3(512), 0, stream>>>(diff, msum, out);
}